// Round 5
// baseline (741.419 us; speedup 1.0000x reference)
//
#include <hip/hip_runtime.h>

#define NN 50000
#define NE 800000
#define HH 128
#define SCAN_BLK 256
#define NBLK ((NN + SCAN_BLK - 1) / SCAN_BLK)   // 196
#define NODEBLKS ((NN + 31) / 32)               // 1563 (32 nodes/block)
#define PSZ ((size_t)NN * 32)                   // halves per panel

typedef _Float16 half8 __attribute__((ext_vector_type(8)));
typedef _Float16 half4 __attribute__((ext_vector_type(4)));
typedef float floatx16 __attribute__((ext_vector_type(16)));

static inline size_t align256(size_t x) { return (x + 255) & ~(size_t)255; }

__device__ inline void ld_epk_nt(const uint2* p, unsigned& s, float& nv) {
    unsigned long long u = __builtin_nontemporal_load((const unsigned long long*)p);
    s = (unsigned)u;
    nv = __uint_as_float((unsigned)(u >> 32));
}

// ---------------- degree histogram ----------------
__global__ void k_deg(const int* __restrict__ dst, int* __restrict__ deg) {
    int e = blockIdx.x * 256 + threadIdx.x;
    if (e < NE) atomicAdd(&deg[dst[e]], 1);
}

// ---------------- two-level scan ----------------
__global__ void k_bsum(const int* __restrict__ deg, int* __restrict__ part) {
    __shared__ int sd[SCAN_BLK];
    int t = threadIdx.x;
    int i = blockIdx.x * SCAN_BLK + t;
    sd[t] = (i < NN) ? deg[i] : 0;
    __syncthreads();
    for (int off = SCAN_BLK / 2; off > 0; off >>= 1) {
        if (t < off) sd[t] += sd[t + off];
        __syncthreads();
    }
    if (t == 0) part[blockIdx.x] = sd[0];
}

__global__ void k_scanpart(const int* __restrict__ part, int* __restrict__ partoff) {
    __shared__ int sd[SCAN_BLK];
    int t = threadIdx.x;
    int v = (t < NBLK) ? part[t] : 0;
    sd[t] = v;
    __syncthreads();
    for (int off = 1; off < SCAN_BLK; off <<= 1) {
        int add = (t >= off) ? sd[t - off] : 0;
        __syncthreads();
        sd[t] += add;
        __syncthreads();
    }
    if (t < NBLK) partoff[t] = sd[t] - v;
}

__global__ void k_apply(const int* __restrict__ deg, const int* __restrict__ partoff,
                        int* __restrict__ offsets, float* __restrict__ dinv) {
    __shared__ int sd[SCAN_BLK];
    int t = threadIdx.x;
    int i = blockIdx.x * SCAN_BLK + t;
    int v = (i < NN) ? deg[i] : 0;
    sd[t] = v;
    __syncthreads();
    for (int off = 1; off < SCAN_BLK; off <<= 1) {
        int add = (t >= off) ? sd[t - off] : 0;
        __syncthreads();
        sd[t] += add;
        __syncthreads();
    }
    if (i < NN) {
        offsets[i] = partoff[blockIdx.x] + sd[t] - v;
        dinv[i] = (v > 0) ? rsqrtf((float)v) : 0.0f;
    }
    if (i == 0) offsets[NN] = NE;
}

// ---------------- CSR fill (sorted by dst), packed (src, norm) records ----------------
__global__ void k_fill(const int* __restrict__ src, const int* __restrict__ dst,
                       const int* __restrict__ offsets, int* __restrict__ cursor,
                       const float* __restrict__ dinv, uint2* __restrict__ epk) {
    int e = blockIdx.x * 256 + threadIdx.x;
    if (e >= NE) return;
    int s = src[e], d = dst[e];
    int pos = atomicAdd(&cursor[d], 1);
    int idx = offsets[d] + pos;
    float nv = dinv[s] * dinv[d];
    epk[idx] = make_uint2((unsigned)s, __float_as_uint(nv));
}

// ---------------- convert x to fp16 (row-major) ----------------
__global__ void k_cvt_x(const float* __restrict__ x, _Float16* __restrict__ xh) {
    int i = blockIdx.x * 256 + threadIdx.x;
    if (i * 4 < NN * HH) {
        float4 v = *(const float4*)(x + (size_t)i * 4);
        half4 h;
        h.x = (_Float16)v.x; h.y = (_Float16)v.y;
        h.z = (_Float16)v.z; h.w = (_Float16)v.w;
        *(half4*)(xh + (size_t)i * 4) = h;
    }
}

// ---------------- convert + transpose weights to fp16 k-major ----------------
__global__ void k_cvt_w(const float* __restrict__ W1, const float* __restrict__ W2,
                        const float* __restrict__ tw,
                        _Float16* __restrict__ W1tP, _Float16* __restrict__ W1tQ,
                        _Float16* __restrict__ W2t, _Float16* __restrict__ TWt) {
    int i = blockIdx.x * 256 + threadIdx.x;
    if (i < 16384) {
        int c = i >> 7, k = i & 127;
        W1tP[c * 128 + k] = (_Float16)W1[k * 128 + c];
        W1tQ[c * 128 + k] = (_Float16)W1[(128 + k) * 128 + c];
    } else if (i < 32768) {
        int j = i - 16384;
        int c = j >> 7, k = j & 127;
        W2t[c * 128 + k] = (_Float16)W2[k * 128 + c];
    } else if (i < 32768 + 3 * 65536) {
        int j = i - 32768;
        int L = j >> 16;
        int c = (j >> 9) & 127;
        int k = j & 511;
        TWt[(size_t)L * 65536 + c * 512 + k] =
            (_Float16)tw[(size_t)L * 65536 + (size_t)(k >> 7) * 16384 + (size_t)(k & 127) * 128 + c];
    }
}

// ---------------- MFMA GEMM ----------------
// A_MODE: 0 = row-major stride lda; 1 = panels [p][NN][32], p = k>>5.
// OUT_MODE: 0 = row-major stride ldo; 1 = panels [p][NN][32], p = col>>5.
template <int KDIM, int A_MODE, int HAS_BIAS, int HAS_DEG, int RELU, int OUT_MODE, typename OutT>
__global__ __launch_bounds__(256) void k_mm(
    const _Float16* __restrict__ A, int lda,
    const _Float16* __restrict__ Bt,
    const float* __restrict__ bias, const int* __restrict__ deg,
    OutT* __restrict__ Out, int ldo, int nrows) {
    __shared__ _Float16 As[128 * 64];
    __shared__ _Float16 Bs[128 * 64];
    const int t = threadIdx.x;
    const int l = t & 63;
    const int w = t >> 6;
    const int wm = w >> 1, wn = w & 1;
    const int row0 = blockIdx.x * 128;

    floatx16 acc[2][2] = {};

    const int srow = t >> 3;   // 0..31
    const int sslot = t & 7;   // 8-half slot within 64-k chunk

    for (int c = 0; c < KDIM / 64; ++c) {
        __syncthreads();
#pragma unroll
        for (int p4 = 0; p4 < 4; ++p4) {
            int r = srow + p4 * 32;
            int g = row0 + r;
            uint4 v = make_uint4(0, 0, 0, 0);
            if (g < nrows) {
                if (A_MODE == 0) {
                    v = *(const uint4*)(A + (size_t)g * lda + c * 64 + sslot * 8);
                } else {
                    int pan = c * 2 + (sslot >> 2);
                    int jj8 = (sslot & 3) * 8;
                    v = *(const uint4*)(A + ((size_t)pan * NN + g) * 32 + jj8);
                }
            }
            *(uint4*)((char*)As + r * 128 + ((sslot * 16) ^ ((r & 7) << 4))) = v;
        }
#pragma unroll
        for (int p4 = 0; p4 < 4; ++p4) {
            int r = srow + p4 * 32;
            uint4 v = *(const uint4*)(Bt + (size_t)r * KDIM + c * 64 + sslot * 8);
            *(uint4*)((char*)Bs + r * 128 + ((sslot * 16) ^ ((r & 7) << 4))) = v;
        }
        __syncthreads();
#pragma unroll
        for (int ks = 0; ks < 4; ++ks) {
            const int koff = ks * 32 + (l >> 5) * 16;
            half8 a0, a1, b0, b1;
            { int r = wm * 64 + (l & 31);      a0 = *(const half8*)((const char*)As + r * 128 + (koff ^ ((r & 7) << 4))); }
            { int r = wm * 64 + 32 + (l & 31); a1 = *(const half8*)((const char*)As + r * 128 + (koff ^ ((r & 7) << 4))); }
            { int r = wn * 64 + (l & 31);      b0 = *(const half8*)((const char*)Bs + r * 128 + (koff ^ ((r & 7) << 4))); }
            { int r = wn * 64 + 32 + (l & 31); b1 = *(const half8*)((const char*)Bs + r * 128 + (koff ^ ((r & 7) << 4))); }
            acc[0][0] = __builtin_amdgcn_mfma_f32_32x32x16_f16(a0, b0, acc[0][0], 0, 0, 0);
            acc[0][1] = __builtin_amdgcn_mfma_f32_32x32x16_f16(a0, b1, acc[0][1], 0, 0, 0);
            acc[1][0] = __builtin_amdgcn_mfma_f32_32x32x16_f16(a1, b0, acc[1][0], 0, 0, 0);
            acc[1][1] = __builtin_amdgcn_mfma_f32_32x32x16_f16(a1, b1, acc[1][1], 0, 0, 0);
        }
    }

#pragma unroll
    for (int mf = 0; mf < 2; ++mf) {
#pragma unroll
        for (int nf = 0; nf < 2; ++nf) {
            const int col = wn * 64 + nf * 32 + (l & 31);
            const float bc = HAS_BIAS ? bias[col] : 0.0f;
#pragma unroll
            for (int r = 0; r < 16; ++r) {
                int row = wm * 64 + mf * 32 + 4 * (l >> 5) + (r & 3) + 8 * (r >> 2);
                int g = row0 + row;
                if (g < nrows) {
                    float v = acc[mf][nf][r];
                    if (HAS_BIAS) v += (HAS_DEG ? (float)deg[g] : 1.0f) * bc;
                    if (RELU) v = fmaxf(v, 0.0f);
                    if (OUT_MODE == 0) {
                        Out[(size_t)g * ldo + col] = (OutT)v;
                    } else {
                        int pan = col >> 5, jj = col & 31;
                        Out[((size_t)pan * NN + g) * 32 + jj] = (OutT)v;
                    }
                }
            }
        }
    }
}

// ---------------- MP edge pass, panelized. grid = 4*NODEBLKS, c-major ----------------
// Sub-pass c: H_c[n][j] = sum_e lrelu(P_c[n][j] + Q_c[src][j]); in-place into P panel c.
__global__ __launch_bounds__(256) void k_edge_mp(_Float16* __restrict__ Pp,
                                                 const _Float16* __restrict__ Qp,
                                                 const int* __restrict__ offsets,
                                                 const uint2* __restrict__ epk) {
    const int t = threadIdx.x;
    const int c = blockIdx.x / NODEBLKS;
    const int n = (blockIdx.x % NODEBLKS) * 32 + (t >> 3);
    if (n >= NN) return;
    const int j4 = (t & 7) * 4;
    _Float16* prow = Pp + ((size_t)c * NN + n) * 32 + j4;
    const _Float16* Qb = Qp + (size_t)c * NN * 32;
    half4 pv = __builtin_bit_cast(half4,
        __builtin_nontemporal_load((const unsigned long long*)prow));
    const float p0 = (float)pv.x, p1 = (float)pv.y, p2 = (float)pv.z, p3 = (float)pv.w;
    const int beg = offsets[n], end = offsets[n + 1];
    float a0 = 0.f, a1 = 0.f, a2 = 0.f, a3 = 0.f;
    int i = beg;
#define LRELU4(vx, vy, vz, vw)                                        \
    a0 += ((vx) > 0.f) ? (vx) : 0.2f * (vx);                          \
    a1 += ((vy) > 0.f) ? (vy) : 0.2f * (vy);                          \
    a2 += ((vz) > 0.f) ? (vz) : 0.2f * (vz);                          \
    a3 += ((vw) > 0.f) ? (vw) : 0.2f * (vw);
    for (; i + 4 <= end; i += 4) {
        unsigned s0, s1, s2, s3; float d0, d1, d2, d3;
        ld_epk_nt(&epk[i + 0], s0, d0);
        ld_epk_nt(&epk[i + 1], s1, d1);
        ld_epk_nt(&epk[i + 2], s2, d2);
        ld_epk_nt(&epk[i + 3], s3, d3);
        half4 q0 = *(const half4*)(Qb + (size_t)s0 * 32 + j4);
        half4 q1 = *(const half4*)(Qb + (size_t)s1 * 32 + j4);
        half4 q2 = *(const half4*)(Qb + (size_t)s2 * 32 + j4);
        half4 q3 = *(const half4*)(Qb + (size_t)s3 * 32 + j4);
        LRELU4(p0 + (float)q0.x, p1 + (float)q0.y, p2 + (float)q0.z, p3 + (float)q0.w)
        LRELU4(p0 + (float)q1.x, p1 + (float)q1.y, p2 + (float)q1.z, p3 + (float)q1.w)
        LRELU4(p0 + (float)q2.x, p1 + (float)q2.y, p2 + (float)q2.z, p3 + (float)q2.w)
        LRELU4(p0 + (float)q3.x, p1 + (float)q3.y, p2 + (float)q3.z, p3 + (float)q3.w)
    }
    for (; i < end; ++i) {
        unsigned s; float d;
        ld_epk_nt(&epk[i], s, d);
        half4 q = *(const half4*)(Qb + (size_t)s * 32 + j4);
        LRELU4(p0 + (float)q.x, p1 + (float)q.y, p2 + (float)q.z, p3 + (float)q.w)
    }
#undef LRELU4
    half4 o;
    o.x = (_Float16)a0; o.y = (_Float16)a1; o.z = (_Float16)a2; o.w = (_Float16)a3;
    *(half4*)prow = o;
}

// ---------------- SpMM, panelized. grid = 4*NODEBLKS, c-major ----------------
__global__ __launch_bounds__(256) void k_spmm(const _Float16* __restrict__ Xin,
                                              _Float16* __restrict__ Yout,
                                              const int* __restrict__ offsets,
                                              const uint2* __restrict__ epk) {
    const int t = threadIdx.x;
    const int c = blockIdx.x / NODEBLKS;
    const int n = (blockIdx.x % NODEBLKS) * 32 + (t >> 3);
    if (n >= NN) return;
    const int j4 = (t & 7) * 4;
    const _Float16* Xb = Xin + (size_t)c * NN * 32;
    const int beg = offsets[n], end = offsets[n + 1];
    float a0 = 0.f, a1 = 0.f, a2 = 0.f, a3 = 0.f;
    int i = beg;
    for (; i + 4 <= end; i += 4) {
        unsigned s0, s1, s2, s3; float d0, d1, d2, d3;
        ld_epk_nt(&epk[i + 0], s0, d0);
        ld_epk_nt(&epk[i + 1], s1, d1);
        ld_epk_nt(&epk[i + 2], s2, d2);
        ld_epk_nt(&epk[i + 3], s3, d3);
        half4 v0 = *(const half4*)(Xb + (size_t)s0 * 32 + j4);
        half4 v1 = *(const half4*)(Xb + (size_t)s1 * 32 + j4);
        half4 v2 = *(const half4*)(Xb + (size_t)s2 * 32 + j4);
        half4 v3 = *(const half4*)(Xb + (size_t)s3 * 32 + j4);
        a0 += d0 * (float)v0.x + d1 * (float)v1.x + d2 * (float)v2.x + d3 * (float)v3.x;
        a1 += d0 * (float)v0.y + d1 * (float)v1.y + d2 * (float)v2.y + d3 * (float)v3.y;
        a2 += d0 * (float)v0.z + d1 * (float)v1.z + d2 * (float)v2.z + d3 * (float)v3.z;
        a3 += d0 * (float)v0.w + d1 * (float)v1.w + d2 * (float)v2.w + d3 * (float)v3.w;
    }
    for (; i < end; ++i) {
        unsigned s; float d;
        ld_epk_nt(&epk[i], s, d);
        half4 v = *(const half4*)(Xb + (size_t)s * 32 + j4);
        a0 += d * (float)v.x; a1 += d * (float)v.y;
        a2 += d * (float)v.z; a3 += d * (float)v.w;
    }
    half4 o;
    o.x = (_Float16)a0; o.y = (_Float16)a1; o.z = (_Float16)a2; o.w = (_Float16)a3;
    *(half4*)(Yout + ((size_t)c * NN + n) * 32 + j4) = o;
}

extern "C" void kernel_launch(void* const* d_in, const int* in_sizes, int n_in,
                              void* d_out, int out_size, void* d_ws, size_t ws_size,
                              hipStream_t stream) {
    const float* x  = (const float*)d_in[0];
    const int*   ei = (const int*)d_in[1];
    const float* W1 = (const float*)d_in[2];
    const float* b1 = (const float*)d_in[3];
    const float* W2 = (const float*)d_in[4];
    const float* b2 = (const float*)d_in[5];
    const float* tw = (const float*)d_in[6];
    const float* tb = (const float*)d_in[7];
    float* out = (float*)d_out;

    const int* srcp = ei;
    const int* dstp = ei + NE;

    char* p = (char*)d_ws;
    auto alloc = [&](size_t bytes) { char* r = p; p += align256(bytes); return r; };
    int*       deg     = (int*)alloc((size_t)NN * 4);
    int*       cursor  = (int*)alloc((size_t)NN * 4);
    int*       offsets = (int*)alloc((size_t)(NN + 1) * 4);
    float*     dinv    = (float*)alloc((size_t)NN * 4);
    int*       part    = (int*)alloc((size_t)NBLK * 4);
    int*       partoff = (int*)alloc((size_t)NBLK * 4);
    uint2*     epk     = (uint2*)alloc((size_t)NE * 8);
    _Float16*  xh      = (_Float16*)alloc((size_t)NN * HH * 2);
    _Float16*  PQp     = (_Float16*)alloc((size_t)NN * 256 * 2);  // panels: P 0-3, Q 4-7
    _Float16*  X4p     = (_Float16*)alloc((size_t)NN * 512 * 2);  // panels: hop h -> 4h..4h+3
    _Float16*  W1tP    = (_Float16*)alloc(16384 * 2);
    _Float16*  W1tQ    = (_Float16*)alloc(16384 * 2);
    _Float16*  W2t     = (_Float16*)alloc(16384 * 2);
    _Float16*  TWt     = (_Float16*)alloc((size_t)3 * 65536 * 2);

    hipMemsetAsync(deg, 0, (size_t)NN * 4, stream);
    hipMemsetAsync(cursor, 0, (size_t)NN * 4, stream);

    k_deg<<<(NE + 255) / 256, 256, 0, stream>>>(dstp, deg);
    k_bsum<<<NBLK, SCAN_BLK, 0, stream>>>(deg, part);
    k_scanpart<<<1, SCAN_BLK, 0, stream>>>(part, partoff);
    k_apply<<<NBLK, SCAN_BLK, 0, stream>>>(deg, partoff, offsets, dinv);
    k_fill<<<(NE + 255) / 256, 256, 0, stream>>>(srcp, dstp, offsets, cursor, dinv, epk);

    k_cvt_x<<<(NN * HH / 4 + 255) / 256, 256, 0, stream>>>(x, xh);
    k_cvt_w<<<(32768 + 3 * 65536 + 255) / 256, 256, 0, stream>>>(W1, W2, tw, W1tP, W1tQ, W2t, TWt);

    const int mmgrid = (NN + 127) / 128;
    _Float16* Qp = PQp + 4 * PSZ;

    // MP layer: P panels = x@W1[:128]+b1 ; Q panels = x@W1[128:]
    k_mm<128, 0, 1, 0, 0, 1, _Float16><<<mmgrid, 256, 0, stream>>>(xh, HH, W1tP, b1, nullptr, PQp, 0, NN);
    k_mm<128, 0, 0, 0, 0, 1, _Float16><<<mmgrid, 256, 0, stream>>>(xh, HH, W1tQ, nullptr, nullptr, Qp, 0, NN);
    // H panels (in-place into P panels)
    k_edge_mp<<<4 * NODEBLKS, 256, 0, stream>>>(PQp, Qp, offsets, epk);
    // x0 = H@W2 + deg*b2 -> X4p hop0 panels
    k_mm<128, 1, 1, 1, 0, 1, _Float16><<<mmgrid, 256, 0, stream>>>(PQp, 0, W2t, b2, deg, X4p, 0, NN);

    // 3 TAGConv layers: 3 panelized hops, then one wide K=512 GEMM
    for (int L = 0; L < 3; ++L) {
        const _Float16* Wt = TWt + (size_t)L * 65536;
        const float* bL = tb + (size_t)L * 128;
        k_spmm<<<4 * NODEBLKS, 256, 0, stream>>>(X4p + 0 * 4 * PSZ, X4p + 1 * 4 * PSZ, offsets, epk);
        k_spmm<<<4 * NODEBLKS, 256, 0, stream>>>(X4p + 1 * 4 * PSZ, X4p + 2 * 4 * PSZ, offsets, epk);
        k_spmm<<<4 * NODEBLKS, 256, 0, stream>>>(X4p + 2 * 4 * PSZ, X4p + 3 * 4 * PSZ, offsets, epk);
        if (L < 2) {
            k_mm<512, 1, 1, 0, 1, 1, _Float16><<<mmgrid, 256, 0, stream>>>(X4p, 0, Wt, bL, nullptr, X4p, 0, NN);
        } else {
            k_mm<512, 1, 1, 0, 1, 0, float><<<mmgrid, 256, 0, stream>>>(X4p, 0, Wt, bL, nullptr, out, HH, NN);
        }
    }
}

// Round 6
// 549.350 us; speedup vs baseline: 1.3496x; 1.3496x over previous
//
#include <hip/hip_runtime.h>

#define NN 50000
#define NE 800000
#define HH 128
#define SCAN_BLK 256
#define NBLK ((NN + SCAN_BLK - 1) / SCAN_BLK)   // 196
#define NB16 ((NN + 15) / 16)                   // 3125 (16 nodes/block)
#define XS ((size_t)NN * HH)                    // halves per hop array

typedef _Float16 half8 __attribute__((ext_vector_type(8)));
typedef _Float16 half4 __attribute__((ext_vector_type(4)));
typedef float floatx16 __attribute__((ext_vector_type(16)));

static inline size_t align256(size_t x) { return (x + 255) & ~(size_t)255; }

__device__ inline void ld_epk_nt(const uint2* p, unsigned& s, float& nv) {
    unsigned long long u = __builtin_nontemporal_load((const unsigned long long*)p);
    s = (unsigned)u;
    nv = __uint_as_float((unsigned)(u >> 32));
}

// ---------------- degree histogram ----------------
__global__ void k_deg(const int* __restrict__ dst, int* __restrict__ deg) {
    int e = blockIdx.x * 256 + threadIdx.x;
    if (e < NE) atomicAdd(&deg[dst[e]], 1);
}

// ---------------- two-level scan ----------------
__global__ void k_bsum(const int* __restrict__ deg, int* __restrict__ part) {
    __shared__ int sd[SCAN_BLK];
    int t = threadIdx.x;
    int i = blockIdx.x * SCAN_BLK + t;
    sd[t] = (i < NN) ? deg[i] : 0;
    __syncthreads();
    for (int off = SCAN_BLK / 2; off > 0; off >>= 1) {
        if (t < off) sd[t] += sd[t + off];
        __syncthreads();
    }
    if (t == 0) part[blockIdx.x] = sd[0];
}

__global__ void k_scanpart(const int* __restrict__ part, int* __restrict__ partoff) {
    __shared__ int sd[SCAN_BLK];
    int t = threadIdx.x;
    int v = (t < NBLK) ? part[t] : 0;
    sd[t] = v;
    __syncthreads();
    for (int off = 1; off < SCAN_BLK; off <<= 1) {
        int add = (t >= off) ? sd[t - off] : 0;
        __syncthreads();
        sd[t] += add;
        __syncthreads();
    }
    if (t < NBLK) partoff[t] = sd[t] - v;
}

__global__ void k_apply(const int* __restrict__ deg, const int* __restrict__ partoff,
                        int* __restrict__ offsets, float* __restrict__ dinv) {
    __shared__ int sd[SCAN_BLK];
    int t = threadIdx.x;
    int i = blockIdx.x * SCAN_BLK + t;
    int v = (i < NN) ? deg[i] : 0;
    sd[t] = v;
    __syncthreads();
    for (int off = 1; off < SCAN_BLK; off <<= 1) {
        int add = (t >= off) ? sd[t - off] : 0;
        __syncthreads();
        sd[t] += add;
        __syncthreads();
    }
    if (i < NN) {
        offsets[i] = partoff[blockIdx.x] + sd[t] - v;
        dinv[i] = (v > 0) ? rsqrtf((float)v) : 0.0f;
    }
    if (i == 0) offsets[NN] = NE;
}

// ---------------- CSR fill (sorted by dst), packed records, nt scatter ----------------
__global__ void k_fill(const int* __restrict__ src, const int* __restrict__ dst,
                       const int* __restrict__ offsets, int* __restrict__ cursor,
                       const float* __restrict__ dinv, uint2* __restrict__ epk) {
    int e = blockIdx.x * 256 + threadIdx.x;
    if (e >= NE) return;
    int s = src[e], d = dst[e];
    int pos = atomicAdd(&cursor[d], 1);
    int idx = offsets[d] + pos;
    float nv = dinv[s] * dinv[d];
    unsigned long long rec = (unsigned long long)(unsigned)s |
                             ((unsigned long long)__float_as_uint(nv) << 32);
    __builtin_nontemporal_store(rec, (unsigned long long*)&epk[idx]);
}

// ---------------- convert x to fp16 ----------------
__global__ void k_cvt_x(const float* __restrict__ x, _Float16* __restrict__ xh) {
    int i = blockIdx.x * 256 + threadIdx.x;
    if (i * 4 < NN * HH) {
        float4 v = *(const float4*)(x + (size_t)i * 4);
        half4 h;
        h.x = (_Float16)v.x; h.y = (_Float16)v.y;
        h.z = (_Float16)v.z; h.w = (_Float16)v.w;
        *(half4*)(xh + (size_t)i * 4) = h;
    }
}

// ---------------- convert + transpose weights to fp16 k-major ----------------
__global__ void k_cvt_w(const float* __restrict__ W1, const float* __restrict__ W2,
                        const float* __restrict__ tw,
                        _Float16* __restrict__ W1tP, _Float16* __restrict__ W1tQ,
                        _Float16* __restrict__ W2t, _Float16* __restrict__ TWt) {
    int i = blockIdx.x * 256 + threadIdx.x;
    if (i < 16384) {
        int c = i >> 7, k = i & 127;
        W1tP[c * 128 + k] = (_Float16)W1[k * 128 + c];
        W1tQ[c * 128 + k] = (_Float16)W1[(128 + k) * 128 + c];
    } else if (i < 32768) {
        int j = i - 16384;
        int c = j >> 7, k = j & 127;
        W2t[c * 128 + k] = (_Float16)W2[k * 128 + c];
    } else if (i < 32768 + 3 * 65536) {
        int j = i - 32768;
        int L = j >> 16;
        int c = (j >> 9) & 127;
        int k = j & 511;
        TWt[(size_t)L * 65536 + c * 512 + k] =
            (_Float16)tw[(size_t)L * 65536 + (size_t)(k >> 7) * 16384 + (size_t)(k & 127) * 128 + c];
    }
}

// ---------------- MFMA GEMM ----------------
// A_MODE: 0 = row-major stride lda; 1 = four stacked [NN][128] arrays, chunk c ->
//         array c>>1, in-row offset (c&1)*64.
template <int KDIM, int A_MODE, int HAS_BIAS, int HAS_DEG, int RELU, typename OutT>
__global__ __launch_bounds__(256) void k_mm(
    const _Float16* __restrict__ A, int lda,
    const _Float16* __restrict__ Bt,
    const float* __restrict__ bias, const int* __restrict__ deg,
    OutT* __restrict__ Out, int ldo, int nrows) {
    __shared__ _Float16 As[128 * 64];
    __shared__ _Float16 Bs[128 * 64];
    const int t = threadIdx.x;
    const int l = t & 63;
    const int w = t >> 6;
    const int wm = w >> 1, wn = w & 1;
    const int row0 = blockIdx.x * 128;

    floatx16 acc[2][2] = {};

    const int srow = t >> 3;   // 0..31
    const int sslot = t & 7;   // 8-half slot within 64-k chunk

    for (int c = 0; c < KDIM / 64; ++c) {
        __syncthreads();
#pragma unroll
        for (int p4 = 0; p4 < 4; ++p4) {
            int r = srow + p4 * 32;
            int g = row0 + r;
            uint4 v = make_uint4(0, 0, 0, 0);
            if (g < nrows) {
                if (A_MODE == 0) {
                    v = *(const uint4*)(A + (size_t)g * lda + c * 64 + sslot * 8);
                } else {
                    v = *(const uint4*)(A + ((size_t)(c >> 1) * NN + g) * HH +
                                        (c & 1) * 64 + sslot * 8);
                }
            }
            *(uint4*)((char*)As + r * 128 + ((sslot * 16) ^ ((r & 7) << 4))) = v;
        }
#pragma unroll
        for (int p4 = 0; p4 < 4; ++p4) {
            int r = srow + p4 * 32;
            uint4 v = *(const uint4*)(Bt + (size_t)r * KDIM + c * 64 + sslot * 8);
            *(uint4*)((char*)Bs + r * 128 + ((sslot * 16) ^ ((r & 7) << 4))) = v;
        }
        __syncthreads();
#pragma unroll
        for (int ks = 0; ks < 4; ++ks) {
            const int koff = ks * 32 + (l >> 5) * 16;
            half8 a0, a1, b0, b1;
            { int r = wm * 64 + (l & 31);      a0 = *(const half8*)((const char*)As + r * 128 + (koff ^ ((r & 7) << 4))); }
            { int r = wm * 64 + 32 + (l & 31); a1 = *(const half8*)((const char*)As + r * 128 + (koff ^ ((r & 7) << 4))); }
            { int r = wn * 64 + (l & 31);      b0 = *(const half8*)((const char*)Bs + r * 128 + (koff ^ ((r & 7) << 4))); }
            { int r = wn * 64 + 32 + (l & 31); b1 = *(const half8*)((const char*)Bs + r * 128 + (koff ^ ((r & 7) << 4))); }
            acc[0][0] = __builtin_amdgcn_mfma_f32_32x32x16_f16(a0, b0, acc[0][0], 0, 0, 0);
            acc[0][1] = __builtin_amdgcn_mfma_f32_32x32x16_f16(a0, b1, acc[0][1], 0, 0, 0);
            acc[1][0] = __builtin_amdgcn_mfma_f32_32x32x16_f16(a1, b0, acc[1][0], 0, 0, 0);
            acc[1][1] = __builtin_amdgcn_mfma_f32_32x32x16_f16(a1, b1, acc[1][1], 0, 0, 0);
        }
    }

#pragma unroll
    for (int mf = 0; mf < 2; ++mf) {
#pragma unroll
        for (int nf = 0; nf < 2; ++nf) {
            const int col = wn * 64 + nf * 32 + (l & 31);
            const float bc = HAS_BIAS ? bias[col] : 0.0f;
#pragma unroll
            for (int r = 0; r < 16; ++r) {
                int row = wm * 64 + mf * 32 + 4 * (l >> 5) + (r & 3) + 8 * (r >> 2);
                int g = row0 + row;
                if (g < nrows) {
                    float v = acc[mf][nf][r];
                    if (HAS_BIAS) v += (HAS_DEG ? (float)deg[g] : 1.0f) * bc;
                    if (RELU) v = fmaxf(v, 0.0f);
                    Out[(size_t)g * ldo + col] = (OutT)v;
                }
            }
        }
    }
}

// ---------------- MP edge pass: H[n] = sum_e lrelu(P[n] + Q[src]); in-place into P.
// 16 nodes/block, 16 lanes x half8 per node.
__global__ __launch_bounds__(256) void k_edge_mp(_Float16* __restrict__ P,
                                                 const _Float16* __restrict__ Q,
                                                 const int* __restrict__ offsets,
                                                 const uint2* __restrict__ epk) {
    const int t = threadIdx.x;
    const int n = blockIdx.x * 16 + (t >> 4);
    if (n >= NN) return;
    const int j8 = (t & 15) * 8;
    const int beg = offsets[n], end = offsets[n + 1];
    half8 pv = *(const half8*)(P + (size_t)n * HH + j8);
    float p[8], a[8];
#pragma unroll
    for (int q = 0; q < 8; ++q) { p[q] = (float)pv[q]; a[q] = 0.f; }
    int i = beg;
    for (; i + 4 <= end; i += 4) {
        unsigned s0, s1, s2, s3; float d0, d1, d2, d3;
        ld_epk_nt(&epk[i + 0], s0, d0);
        ld_epk_nt(&epk[i + 1], s1, d1);
        ld_epk_nt(&epk[i + 2], s2, d2);
        ld_epk_nt(&epk[i + 3], s3, d3);
        half8 q0 = *(const half8*)(Q + (size_t)s0 * HH + j8);
        half8 q1 = *(const half8*)(Q + (size_t)s1 * HH + j8);
        half8 q2 = *(const half8*)(Q + (size_t)s2 * HH + j8);
        half8 q3 = *(const half8*)(Q + (size_t)s3 * HH + j8);
#pragma unroll
        for (int q = 0; q < 8; ++q) {
            float v0 = p[q] + (float)q0[q];
            float v1 = p[q] + (float)q1[q];
            float v2 = p[q] + (float)q2[q];
            float v3 = p[q] + (float)q3[q];
            a[q] += ((v0 > 0.f) ? v0 : 0.2f * v0) + ((v1 > 0.f) ? v1 : 0.2f * v1) +
                    ((v2 > 0.f) ? v2 : 0.2f * v2) + ((v3 > 0.f) ? v3 : 0.2f * v3);
        }
    }
    for (; i < end; ++i) {
        unsigned s; float d;
        ld_epk_nt(&epk[i], s, d);
        half8 qv = *(const half8*)(Q + (size_t)s * HH + j8);
#pragma unroll
        for (int q = 0; q < 8; ++q) {
            float v = p[q] + (float)qv[q];
            a[q] += (v > 0.f) ? v : 0.2f * v;
        }
    }
    half8 o;
#pragma unroll
    for (int q = 0; q < 8; ++q) o[q] = (_Float16)a[q];
    *(half8*)(P + (size_t)n * HH + j8) = o;
}

// ---------------- SpMM: Y[n] = sum_e norm_e * X[src], dense [NN][128] arrays ----------------
__global__ __launch_bounds__(256) void k_spmm(const _Float16* __restrict__ Xin,
                                              _Float16* __restrict__ Yout,
                                              const int* __restrict__ offsets,
                                              const uint2* __restrict__ epk) {
    const int t = threadIdx.x;
    const int n = blockIdx.x * 16 + (t >> 4);
    if (n >= NN) return;
    const int j8 = (t & 15) * 8;
    const int beg = offsets[n], end = offsets[n + 1];
    float a[8] = {};
    int i = beg;
    for (; i + 4 <= end; i += 4) {
        unsigned s0, s1, s2, s3; float d0, d1, d2, d3;
        ld_epk_nt(&epk[i + 0], s0, d0);
        ld_epk_nt(&epk[i + 1], s1, d1);
        ld_epk_nt(&epk[i + 2], s2, d2);
        ld_epk_nt(&epk[i + 3], s3, d3);
        half8 v0 = *(const half8*)(Xin + (size_t)s0 * HH + j8);
        half8 v1 = *(const half8*)(Xin + (size_t)s1 * HH + j8);
        half8 v2 = *(const half8*)(Xin + (size_t)s2 * HH + j8);
        half8 v3 = *(const half8*)(Xin + (size_t)s3 * HH + j8);
#pragma unroll
        for (int q = 0; q < 8; ++q) {
            a[q] += d0 * (float)v0[q] + d1 * (float)v1[q] +
                    d2 * (float)v2[q] + d3 * (float)v3[q];
        }
    }
    for (; i < end; ++i) {
        unsigned s; float d;
        ld_epk_nt(&epk[i], s, d);
        half8 v = *(const half8*)(Xin + (size_t)s * HH + j8);
#pragma unroll
        for (int q = 0; q < 8; ++q) a[q] += d * (float)v[q];
    }
    half8 o;
#pragma unroll
    for (int q = 0; q < 8; ++q) o[q] = (_Float16)a[q];
    *(half8*)(Yout + (size_t)n * HH + j8) = o;
}

extern "C" void kernel_launch(void* const* d_in, const int* in_sizes, int n_in,
                              void* d_out, int out_size, void* d_ws, size_t ws_size,
                              hipStream_t stream) {
    const float* x  = (const float*)d_in[0];
    const int*   ei = (const int*)d_in[1];
    const float* W1 = (const float*)d_in[2];
    const float* b1 = (const float*)d_in[3];
    const float* W2 = (const float*)d_in[4];
    const float* b2 = (const float*)d_in[5];
    const float* tw = (const float*)d_in[6];
    const float* tb = (const float*)d_in[7];
    float* out = (float*)d_out;

    const int* srcp = ei;
    const int* dstp = ei + NE;

    char* p = (char*)d_ws;
    auto alloc = [&](size_t bytes) { char* r = p; p += align256(bytes); return r; };
    int*       deg     = (int*)alloc((size_t)NN * 4);
    int*       cursor  = (int*)alloc((size_t)NN * 4);
    int*       offsets = (int*)alloc((size_t)(NN + 1) * 4);
    float*     dinv    = (float*)alloc((size_t)NN * 4);
    int*       part    = (int*)alloc((size_t)NBLK * 4);
    int*       partoff = (int*)alloc((size_t)NBLK * 4);
    uint2*     epk     = (uint2*)alloc((size_t)NE * 8);
    _Float16*  xh      = (_Float16*)alloc(XS * 2);
    _Float16*  P       = (_Float16*)alloc(XS * 2);
    _Float16*  Q       = (_Float16*)alloc(XS * 2);
    _Float16*  X4      = (_Float16*)alloc(4 * XS * 2);   // x0|x1|x2|x3, each [NN][128]
    _Float16*  W1tP    = (_Float16*)alloc(16384 * 2);
    _Float16*  W1tQ    = (_Float16*)alloc(16384 * 2);
    _Float16*  W2t     = (_Float16*)alloc(16384 * 2);
    _Float16*  TWt     = (_Float16*)alloc((size_t)3 * 65536 * 2);

    hipMemsetAsync(deg, 0, (size_t)NN * 4, stream);
    hipMemsetAsync(cursor, 0, (size_t)NN * 4, stream);

    k_deg<<<(NE + 255) / 256, 256, 0, stream>>>(dstp, deg);
    k_bsum<<<NBLK, SCAN_BLK, 0, stream>>>(deg, part);
    k_scanpart<<<1, SCAN_BLK, 0, stream>>>(part, partoff);
    k_apply<<<NBLK, SCAN_BLK, 0, stream>>>(deg, partoff, offsets, dinv);
    k_fill<<<(NE + 255) / 256, 256, 0, stream>>>(srcp, dstp, offsets, cursor, dinv, epk);

    k_cvt_x<<<(NN * HH / 4 + 255) / 256, 256, 0, stream>>>(x, xh);
    k_cvt_w<<<(32768 + 3 * 65536 + 255) / 256, 256, 0, stream>>>(W1, W2, tw, W1tP, W1tQ, W2t, TWt);

    const int mmgrid = (NN + 127) / 128;

    // MP layer: P = x@W1[:128]+b1 ; Q = x@W1[128:]
    k_mm<128, 0, 1, 0, 0, _Float16><<<mmgrid, 256, 0, stream>>>(xh, HH, W1tP, b1, nullptr, P, HH, NN);
    k_mm<128, 0, 0, 0, 0, _Float16><<<mmgrid, 256, 0, stream>>>(xh, HH, W1tQ, nullptr, nullptr, Q, HH, NN);
    // H = sum_e lrelu(P[n]+Q[s]) -> in place into P
    k_edge_mp<<<NB16, 256, 0, stream>>>(P, Q, offsets, epk);
    // x0 = H@W2 + deg*b2 -> X4[0]
    k_mm<128, 0, 1, 1, 0, _Float16><<<mmgrid, 256, 0, stream>>>(P, HH, W2t, b2, deg, X4, HH, NN);

    // 3 TAGConv layers: 3 hops into dense arrays, then one wide K=512 GEMM
    for (int L = 0; L < 3; ++L) {
        const _Float16* Wt = TWt + (size_t)L * 65536;
        const float* bL = tb + (size_t)L * 128;
        k_spmm<<<NB16, 256, 0, stream>>>(X4 + 0 * XS, X4 + 1 * XS, offsets, epk);
        k_spmm<<<NB16, 256, 0, stream>>>(X4 + 1 * XS, X4 + 2 * XS, offsets, epk);
        k_spmm<<<NB16, 256, 0, stream>>>(X4 + 2 * XS, X4 + 3 * XS, offsets, epk);
        if (L < 2) {
            k_mm<512, 1, 1, 0, 1, _Float16><<<mmgrid, 256, 0, stream>>>(X4, 0, Wt, bL, nullptr, X4, HH, NN);
        } else {
            k_mm<512, 1, 1, 0, 1, float><<<mmgrid, 256, 0, stream>>>(X4, 0, Wt, bL, nullptr, out, HH, NN);
        }
    }
}